// Round 2
// baseline (110.070 us; speedup 1.0000x reference)
//
#include <hip/hip_runtime.h>
#include <hip/hip_bf16.h>
#include <math.h>

#define SEQ   2048
#define DIM   512
#define NH    8
#define DH    64
#define LR    7
#define TI    8
#define NROW  (TI + 2 * LR)   // 22

typedef __bf16 bf16_t;
typedef __bf16 bf16x8 __attribute__((ext_vector_type(8)));
typedef float  f32x4  __attribute__((ext_vector_type(4)));

typedef __attribute__((address_space(3))) void  lds_void;
typedef __attribute__((address_space(1))) const void gbl_cvoid;

// ---------------------------------------------------------------------------
// Kernel 0 (prep): Wt[n][k] = bf16(W[k][n]).  128 blocks (64x64 tiles).
// The hs->bf16 pass is gone: the GEMM now reads hs fp32 directly.
// ---------------------------------------------------------------------------
__global__ __launch_bounds__(256) void prep(
    const float* __restrict__ Wq, const float* __restrict__ Wk,
    bf16_t* __restrict__ Wt)             // [1024][512]
{
    const int tid = threadIdx.x;
    __shared__ float tile[64][68];
    const int t  = blockIdx.x;
    const int k0 = (t & 7) * 64;
    const int n0 = (t >> 3) * 64;
    const float* W = (n0 < DIM) ? Wq : Wk;
    const int nn0 = n0 & (DIM - 1);

    #pragma unroll
    for (int ph = 0; ph < 4; ++ph) {
        const int kk = ph * 16 + (tid >> 4);
        const int nn = (tid & 15) * 4;
        const float4 v = *(const float4*)(W + (size_t)(k0 + kk) * DIM + nn0 + nn);
        tile[kk][nn + 0] = v.x; tile[kk][nn + 1] = v.y;
        tile[kk][nn + 2] = v.z; tile[kk][nn + 3] = v.w;
    }
    __syncthreads();
    #pragma unroll
    for (int ph = 0; ph < 4; ++ph) {
        const int nn = ph * 16 + (tid >> 4);
        const int kk = (tid & 15) * 4;
        union { bf16_t b[4]; ushort4 u; } cv;
        #pragma unroll
        for (int u = 0; u < 4; ++u) cv.b[u] = (bf16_t)tile[kk + u][nn];
        *(ushort4*)(Wt + (size_t)(n0 + nn) * DIM + k0 + kk) = cv.u;
    }
}

// ---------------------------------------------------------------------------
// Kernel 1: qkb[4096][1024] (bf16) = bf16(hs) @ Wt^T.
// R0's proven structure (64x128 tile, BK=64 twin 32-k panels, 2 blocks/CU,
// plain __syncthreads pipeline) with ONE change: A is staged as fp32
// directly from hs via global_load_lds (per-lane source addressing), and
// converted to bf16 at fragment-read time.  f32 A panels have 128B row
// stride -> XOR-swizzle (slot ^ row&7) on BOTH the glds source and the
// ds_read side to stay at the 8-cycle LDS floor.  B path unchanged.
// ---------------------------------------------------------------------------
__global__ __launch_bounds__(256) void qk_gemm_mfma(
    const float*  __restrict__ A,    // hs fp32 [4096][512]
    const bf16_t* __restrict__ Bt,   // [1024][512]
    bf16_t* __restrict__ C)          // [4096][1024]
{
    __shared__ __align__(16) float  Asf[2][64 * 32];              // 8 KB each
    __shared__ __align__(16) bf16_t Bs0[128 * 32], Bs1[128 * 32]; // 8 KB each

    const int tid  = threadIdx.x;
    const int wave = tid >> 6;
    const int lane = tid & 63;
    const int l15  = lane & 15;
    const int quad = lane >> 4;
    const int wm   = (wave >> 1) * 32;
    const int wn_  = (wave & 1) * 64;
    const int m0   = blockIdx.x * 64;
    const int n0   = blockIdx.y * 128;

    // B staging (bf16), unchanged from R0:
    const int srow = lane >> 2;          // 0..15
    const int scol = (lane & 3) * 8;     // 0,8,16,24 (bf16)
    const bf16_t* bgp = Bt + (size_t)(n0 + wave * 32 + srow) * DIM + scol;
    bf16_t* bl0 = Bs0 + wave * 32 * 32;
    bf16_t* bl1 = Bs1 + wave * 32 * 32;

    // A staging (fp32): each glds covers 8 rows x 32 f32.  Source slot is
    // pre-swizzled so phys slot p at row r holds logical slot p ^ (r&7).
    const int arow  = lane >> 3;               // 0..7
    const int aslot = (lane & 7) ^ arow;       // swizzled 16B slot (4 f32)
    const float* agp = A + (size_t)(m0 + wave * 16 + arow) * DIM + aslot * 4;

    f32x4 acc[2][4] = {};

    for (int k0 = 0; k0 < DIM; k0 += 64) {
        #pragma unroll
        for (int s = 0; s < 2; ++s) {
            #pragma unroll
            for (int g = 0; g < 2; ++g) {
                __builtin_amdgcn_global_load_lds(
                    (gbl_cvoid*)(agp + (size_t)g * 8 * DIM + k0 + s * 32),
                    (lds_void*)(Asf[s] + (wave * 16 + g * 8) * 32), 16, 0, 0);
            }
        }
        __builtin_amdgcn_global_load_lds((gbl_cvoid*)(bgp + k0),      (lds_void*)bl0, 16, 0, 0);
        __builtin_amdgcn_global_load_lds((gbl_cvoid*)(bgp + k0 + 32), (lds_void*)bl1, 16, 0, 0);
        __builtin_amdgcn_global_load_lds((gbl_cvoid*)(bgp + 16 * DIM + k0),      (lds_void*)(bl0 + 16 * 32), 16, 0, 0);
        __builtin_amdgcn_global_load_lds((gbl_cvoid*)(bgp + 16 * DIM + k0 + 32), (lds_void*)(bl1 + 16 * 32), 16, 0, 0);
        __syncthreads();

        #pragma unroll
        for (int s = 0; s < 2; ++s) {
            const float*  PA = Asf[s];
            const bf16_t* PB = s ? Bs1 : Bs0;
            bf16x8 af[2], bfv[4];
            const int hx = l15 & 7;
            #pragma unroll
            for (int mi = 0; mi < 2; ++mi) {
                const float* rp = PA + (wm + mi * 16 + l15) * 32;
                const f32x4 u0 = *(const f32x4*)(rp + (((quad << 1)    ) ^ hx) * 4);
                const f32x4 u1 = *(const f32x4*)(rp + (((quad << 1) | 1) ^ hx) * 4);
                union { bf16_t b[8]; bf16x8 v; } cv;
                cv.b[0]=(bf16_t)u0[0]; cv.b[1]=(bf16_t)u0[1]; cv.b[2]=(bf16_t)u0[2]; cv.b[3]=(bf16_t)u0[3];
                cv.b[4]=(bf16_t)u1[0]; cv.b[5]=(bf16_t)u1[1]; cv.b[6]=(bf16_t)u1[2]; cv.b[7]=(bf16_t)u1[3];
                af[mi] = cv.v;
            }
            #pragma unroll
            for (int ni = 0; ni < 4; ++ni)
                bfv[ni] = *(const bf16x8*)(PB + (wn_ + ni * 16 + l15) * 32 + quad * 8);
            #pragma unroll
            for (int mi = 0; mi < 2; ++mi)
                #pragma unroll
                for (int ni = 0; ni < 4; ++ni)
                    acc[mi][ni] = __builtin_amdgcn_mfma_f32_16x16x32_bf16(
                        af[mi], bfv[ni], acc[mi][ni], 0, 0, 0);
        }
        __syncthreads();
    }

    #pragma unroll
    for (int mi = 0; mi < 2; ++mi) {
        #pragma unroll
        for (int ni = 0; ni < 4; ++ni) {
            const int col = n0 + wn_ + ni * 16 + l15;
            #pragma unroll
            for (int r = 0; r < 4; ++r) {
                const int row = m0 + wm + mi * 16 + quad * 4 + r;
                C[(size_t)row * 1024 + col] = (bf16_t)acc[mi][ni][r];
            }
        }
    }
}

// ---------------------------------------------------------------------------
// Kernel 2: block = (b, 8-row i-tile), all heads.
// P1: glds-stage Qb[16][512], Kb[32][512] bf16 from qkb.
// P2: scores via MFMA (each wave: 2 heads, 2 n-tiles, 2 k-steps).
// P3: softmax with position masking (seq edges handled here).
// P4: glds-stage fp32 hs band over the Qb/Kb region.  P5: context.
// ---------------------------------------------------------------------------
__global__ __launch_bounds__(256) void local_attn4(
    const float* __restrict__ hs,    // [B,SEQ,DIM] fp32
    const bf16_t* __restrict__ qkb,  // [4096][1024] bf16 (q | k)
    float* __restrict__ out)         // [B,NH,SEQ,DIM]
{
    __shared__ __align__(16) char uni[49152];   // Qb(16K)+Kb(32K) then band(44K)
    bf16_t* Qb   = (bf16_t*)uni;                // [16][512]
    bf16_t* Kb   = (bf16_t*)(uni + 16384);      // [32][512]
    float*  band = (float*)uni;                 // [22][512]
    __shared__ float sw2[NH][TI][24];
    __shared__ float wn[NH * TI][17];           // +1 pad

    const int tid  = threadIdx.x;
    const int wave = tid >> 6;
    const int lane = tid & 63;
    const int l15  = lane & 15;
    const int quad = lane >> 4;
    const int i0   = blockIdx.x * TI;
    const int b    = blockIdx.y;

    // ---- P1: stage Q rows (8) and K band rows (22) as bf16 via glds ----
    for (int r = wave; r < TI; r += 4) {
        const bf16_t* g = qkb + (size_t)(b * SEQ + i0 + r) * 1024 + lane * 8;
        __builtin_amdgcn_global_load_lds((gbl_cvoid*)g, (lds_void*)(Qb + r * DIM), 16, 0, 0);
    }
    for (int r = wave; r < NROW; r += 4) {
        int jg = i0 - LR + r;
        jg = jg < 0 ? 0 : (jg > SEQ - 1 ? SEQ - 1 : jg);
        const bf16_t* g = qkb + (size_t)(b * SEQ + jg) * 1024 + DIM + lane * 8;
        __builtin_amdgcn_global_load_lds((gbl_cvoid*)g, (lds_void*)(Kb + r * DIM), 16, 0, 0);
    }
    __syncthreads();

    // ---- P2: MFMA scores.  wave handles heads 2w, 2w+1. ----
    #pragma unroll
    for (int hh = 0; hh < 2; ++hh) {
        const int h = wave * 2 + hh;
        f32x4 sacc[2] = {};
        #pragma unroll
        for (int s = 0; s < 2; ++s) {
            const bf16x8 aq = *(const bf16x8*)(Qb + l15 * DIM + h * DH + s * 32 + quad * 8);
            #pragma unroll
            for (int t = 0; t < 2; ++t) {
                const bf16x8 bk = *(const bf16x8*)(Kb + (t * 16 + l15) * DIM + h * DH + s * 32 + quad * 8);
                sacc[t] = __builtin_amdgcn_mfma_f32_16x16x32_bf16(aq, bk, sacc[t], 0, 0, 0);
            }
        }
        #pragma unroll
        for (int t = 0; t < 2; ++t) {
            const int jj = t * 16 + l15;
            if (jj < NROW) {
                #pragma unroll
                for (int r = 0; r < 4; ++r) {
                    const int ii = quad * 4 + r;
                    if (ii < TI) sw2[h][ii][jj] = sacc[t][r] * 0.125f;
                }
            }
        }
    }
    __syncthreads();

    // ---- P4: stage fp32 hs band via glds (over Qb/Kb region) ----
    for (int r = wave; r < NROW; r += 4) {
        int jg = i0 - LR + r;
        jg = jg < 0 ? 0 : (jg > SEQ - 1 ? SEQ - 1 : jg);
        const float* g0 = hs + ((size_t)b * SEQ + jg) * DIM + lane * 4;
        __builtin_amdgcn_global_load_lds((gbl_cvoid*)g0,         (lds_void*)(band + r * DIM),       16, 0, 0);
        __builtin_amdgcn_global_load_lds((gbl_cvoid*)(g0 + 256), (lds_void*)(band + r * DIM + 256), 16, 0, 0);
    }

    // ---- P3: softmax (tid<64), position-masked ----
    if (tid < NH * TI) {
        const int h  = tid >> 3;
        const int ii = tid & (TI - 1);
        const int i  = i0 + ii;
        float v[15], m = -1e30f;
        #pragma unroll
        for (int t = 0; t < 15; ++t) {
            const int jg = i - LR + t;
            v[t] = (jg >= 0 && jg < SEQ) ? sw2[h][ii][ii + t] : -1e30f;
            m = fmaxf(m, v[t]);
        }
        float sum = 0.f;
        #pragma unroll
        for (int t = 0; t < 15; ++t) { v[t] = __expf(v[t] - m); sum += v[t]; }
        const float inv = 1.f / sum;
        #pragma unroll
        for (int t = 0; t < 15; ++t) wn[tid][t] = v[t] * inv;
    }
    __syncthreads();

    // ---- P5: context ----
    {
        const int h  = tid >> 5;                // 0..7
        const int iq = (tid >> 4) & 1;          // 0..1
        const int dg = tid & 15;                // 0..15

        float wreg[4][15];
        #pragma unroll
        for (int t = 0; t < 4; ++t) {
            const int pair = h * TI + iq * 4 + t;
            #pragma unroll
            for (int j = 0; j < 15; ++j) wreg[t][j] = wn[pair][j];
        }

        const int r0 = iq * 4;
        float* op = out + ((size_t)(b * NH + h) * SEQ + i0 + iq * 4) * DIM;

        for (int c = 0; c < DIM / 64; ++c) {
            const int dbase = c * 64 + dg * 4;
            float4 a0 = {0,0,0,0}, a1 = {0,0,0,0}, a2 = {0,0,0,0}, a3 = {0,0,0,0};
            #pragma unroll
            for (int rr = 0; rr < 18; ++rr) {
                const float4 v = *(const float4*)&band[(r0 + rr) * DIM + dbase];
                if (rr <= 14) {
                    const float w = wreg[0][rr];
                    a0.x += w * v.x; a0.y += w * v.y; a0.z += w * v.z; a0.w += w * v.w;
                }
                if (rr >= 1 && rr <= 15) {
                    const float w = wreg[1][rr - 1];
                    a1.x += w * v.x; a1.y += w * v.y; a1.z += w * v.z; a1.w += w * v.w;
                }
                if (rr >= 2 && rr <= 16) {
                    const float w = wreg[2][rr - 2];
                    a2.x += w * v.x; a2.y += w * v.y; a2.z += w * v.z; a2.w += w * v.w;
                }
                if (rr >= 3) {
                    const float w = wreg[3][rr - 3];
                    a3.x += w * v.x; a3.y += w * v.y; a3.z += w * v.z; a3.w += w * v.w;
                }
            }
            *(float4*)(op + (size_t)0 * DIM + dbase) = a0;
            *(float4*)(op + (size_t)1 * DIM + dbase) = a1;
            *(float4*)(op + (size_t)2 * DIM + dbase) = a2;
            *(float4*)(op + (size_t)3 * DIM + dbase) = a3;
        }
    }
}

// ---------------------------------------------------------------------------
extern "C" void kernel_launch(void* const* d_in, const int* in_sizes, int n_in,
                              void* d_out, int out_size, void* d_ws, size_t ws_size,
                              hipStream_t stream)
{
    const float* hs = (const float*)d_in[0];
    const float* Wq = (const float*)d_in[1];
    const float* Wk = (const float*)d_in[2];
    float* out = (float*)d_out;

    bf16_t* Wt  = (bf16_t*)d_ws;                          // 1 MB
    bf16_t* qkb = (bf16_t*)((char*)d_ws + (1 << 20));     // 8 MB

    prep<<<128, 256, 0, stream>>>(Wq, Wk, Wt);
    qk_gemm_mfma<<<dim3(4096 / 64, 1024 / 128), 256, 0, stream>>>(hs, Wt, qkb);
    local_attn4<<<dim3(SEQ / TI, 2), 256, 0, stream>>>(hs, qkb, out);
}

// Round 3
// 103.454 us; speedup vs baseline: 1.0640x; 1.0640x over previous
//
#include <hip/hip_runtime.h>
#include <hip/hip_bf16.h>
#include <math.h>

#define SEQ   2048
#define DIM   512
#define NH    8
#define DH    64
#define LR    7
#define TI    8
#define NROW  (TI + 2 * LR)   // 22

typedef __bf16 bf16_t;
typedef __bf16 bf16x8 __attribute__((ext_vector_type(8)));
typedef float  f32x4  __attribute__((ext_vector_type(4)));

typedef __attribute__((address_space(3))) void  lds_void;
typedef __attribute__((address_space(1))) const void gbl_cvoid;

// ---------------------------------------------------------------------------
// Kernel 0 (prep): blocks [0,1024): hsb = bf16(hs)
//                  blocks [1024,1152): Wt[n][k] = bf16(W[k][n])
// (exact R0 version)
// ---------------------------------------------------------------------------
__global__ __launch_bounds__(256) void prep(
    const float* __restrict__ hs,
    const float* __restrict__ Wq, const float* __restrict__ Wk,
    bf16_t* __restrict__ hsb,            // [4096][512]
    bf16_t* __restrict__ Wt)             // [1024][512]
{
    const int tid = threadIdx.x;
    const int bx  = blockIdx.x;

    if (bx < 1024) {
        const size_t base = ((size_t)bx * 256 + tid) * 8;
        const float4 f0 = *(const float4*)(hs + base);
        const float4 f1 = *(const float4*)(hs + base + 4);
        union { bf16_t b[8]; uint4 u; } cv;
        cv.b[0]=(bf16_t)f0.x; cv.b[1]=(bf16_t)f0.y; cv.b[2]=(bf16_t)f0.z; cv.b[3]=(bf16_t)f0.w;
        cv.b[4]=(bf16_t)f1.x; cv.b[5]=(bf16_t)f1.y; cv.b[6]=(bf16_t)f1.z; cv.b[7]=(bf16_t)f1.w;
        *(uint4*)(hsb + base) = cv.u;
        return;
    }

    __shared__ float tile[64][68];
    const int t  = bx - 1024;
    const int k0 = (t & 7) * 64;
    const int n0 = (t >> 3) * 64;
    const float* W = (n0 < DIM) ? Wq : Wk;
    const int nn0 = n0 & (DIM - 1);

    #pragma unroll
    for (int ph = 0; ph < 4; ++ph) {
        const int kk = ph * 16 + (tid >> 4);
        const int nn = (tid & 15) * 4;
        const float4 v = *(const float4*)(W + (size_t)(k0 + kk) * DIM + nn0 + nn);
        tile[kk][nn + 0] = v.x; tile[kk][nn + 1] = v.y;
        tile[kk][nn + 2] = v.z; tile[kk][nn + 3] = v.w;
    }
    __syncthreads();
    #pragma unroll
    for (int ph = 0; ph < 4; ++ph) {
        const int nn = ph * 16 + (tid >> 4);
        const int kk = (tid & 15) * 4;
        union { bf16_t b[4]; ushort4 u; } cv;
        #pragma unroll
        for (int u = 0; u < 4; ++u) cv.b[u] = (bf16_t)tile[kk + u][nn];
        *(ushort4*)(Wt + (size_t)(n0 + nn) * DIM + k0 + kk) = cv.u;
    }
}

// ---------------------------------------------------------------------------
// Kernel 1: qkb[4096][1024] (bf16) = hsb @ Wt^T.
// R0's 64x128 tile / BK=64 twin-32 panels / 2+ blocks per CU, with ONE
// change: LDS double-buffered + counted-vmcnt pipeline.  Each wave issues
// next tile's 6 global_load_lds BEFORE waiting vmcnt(6) (its current 6
// done, next 6 stay in flight across the raw barrier) -> no vmcnt(0)
// drain in the main loop.  Staging addresses, fragment reads, MFMA
// schedule identical to R0.
// ---------------------------------------------------------------------------
__global__ __launch_bounds__(256) void qk_gemm_mfma(
    const bf16_t* __restrict__ A,    // [4096][512]
    const bf16_t* __restrict__ Bt,   // [1024][512]
    bf16_t* __restrict__ C)          // [4096][1024]
{
    __shared__ __align__(16) bf16_t As[2][2][64 * 32];    // [buf][khalf] 4 KB each
    __shared__ __align__(16) bf16_t Bs[2][2][128 * 32];   // [buf][khalf] 8 KB each

    const int tid  = threadIdx.x;
    const int wave = tid >> 6;
    const int lane = tid & 63;
    const int l15  = lane & 15;
    const int quad = lane >> 4;
    const int wm   = (wave >> 1) * 32;
    const int wn_  = (wave & 1) * 64;
    const int m0   = blockIdx.x * 64;
    const int n0   = blockIdx.y * 128;

    const int srow = lane >> 2;          // 0..15
    const int scol = (lane & 3) * 8;     // 0,8,16,24

    const bf16_t* agp = A  + (size_t)(m0 + wave * 16 + srow) * DIM + scol;
    const bf16_t* bgp = Bt + (size_t)(n0 + wave * 32 + srow) * DIM + scol;

    f32x4 acc[2][4] = {};

    // 6 glds per wave per stage: A half0, A half1, B rows0-15 half0/1,
    // B rows16-31 half0/1  (same addresses as R0).
    auto GSTAGE = [&](int buf, int k0) {
        bf16_t* al0 = As[buf][0] + wave * 16 * 32;
        bf16_t* al1 = As[buf][1] + wave * 16 * 32;
        bf16_t* bl0 = Bs[buf][0] + wave * 32 * 32;
        bf16_t* bl1 = Bs[buf][1] + wave * 32 * 32;
        __builtin_amdgcn_global_load_lds((gbl_cvoid*)(agp + k0),      (lds_void*)al0, 16, 0, 0);
        __builtin_amdgcn_global_load_lds((gbl_cvoid*)(agp + k0 + 32), (lds_void*)al1, 16, 0, 0);
        __builtin_amdgcn_global_load_lds((gbl_cvoid*)(bgp + k0),      (lds_void*)bl0, 16, 0, 0);
        __builtin_amdgcn_global_load_lds((gbl_cvoid*)(bgp + k0 + 32), (lds_void*)bl1, 16, 0, 0);
        __builtin_amdgcn_global_load_lds((gbl_cvoid*)(bgp + 16 * DIM + k0),      (lds_void*)(bl0 + 16 * 32), 16, 0, 0);
        __builtin_amdgcn_global_load_lds((gbl_cvoid*)(bgp + 16 * DIM + k0 + 32), (lds_void*)(bl1 + 16 * 32), 16, 0, 0);
    };

    GSTAGE(0, 0);                                   // 6 in flight (buf 0)
    int cur = 0;
    for (int kk = 0; kk < 8; ++kk) {
        if (kk < 7) {
            GSTAGE(cur ^ 1, (kk + 1) * 64);         // +6 -> 12 in flight
            asm volatile("s_waitcnt vmcnt(6)" ::: "memory");   // cur's 6 landed
        } else {
            asm volatile("s_waitcnt vmcnt(0)" ::: "memory");
        }
        __builtin_amdgcn_s_barrier();               // cur visible to all waves

        #pragma unroll
        for (int s = 0; s < 2; ++s) {
            const bf16_t* PA = As[cur][s];
            const bf16_t* PB = Bs[cur][s];
            bf16x8 af[2], bfv[4];
            #pragma unroll
            for (int mi = 0; mi < 2; ++mi)
                af[mi] = *(const bf16x8*)(PA + (wm + mi * 16 + l15) * 32 + quad * 8);
            #pragma unroll
            for (int ni = 0; ni < 4; ++ni)
                bfv[ni] = *(const bf16x8*)(PB + (wn_ + ni * 16 + l15) * 32 + quad * 8);
            #pragma unroll
            for (int mi = 0; mi < 2; ++mi)
                #pragma unroll
                for (int ni = 0; ni < 4; ++ni)
                    acc[mi][ni] = __builtin_amdgcn_mfma_f32_16x16x32_bf16(
                        af[mi], bfv[ni], acc[mi][ni], 0, 0, 0);
        }
        __builtin_amdgcn_s_barrier();               // release cur for restage
        cur ^= 1;
    }

    #pragma unroll
    for (int mi = 0; mi < 2; ++mi) {
        #pragma unroll
        for (int ni = 0; ni < 4; ++ni) {
            const int col = n0 + wn_ + ni * 16 + l15;
            #pragma unroll
            for (int r = 0; r < 4; ++r) {
                const int row = m0 + wm + mi * 16 + quad * 4 + r;
                C[(size_t)row * 1024 + col] = (bf16_t)acc[mi][ni][r];
            }
        }
    }
}

// ---------------------------------------------------------------------------
// Kernel 2: block = (b, 8-row i-tile), all heads.  (exact R0 version,
// wn padded 16->17 to break the 32-way P3 store conflict)
// ---------------------------------------------------------------------------
__global__ __launch_bounds__(256) void local_attn4(
    const float* __restrict__ hs,    // [B,SEQ,DIM] fp32
    const bf16_t* __restrict__ qkb,  // [4096][1024] bf16 (q | k)
    float* __restrict__ out)         // [B,NH,SEQ,DIM]
{
    __shared__ __align__(16) char uni[49152];   // Qb(16K)+Kb(32K) then band(44K)
    bf16_t* Qb   = (bf16_t*)uni;                // [16][512]
    bf16_t* Kb   = (bf16_t*)(uni + 16384);      // [32][512]
    float*  band = (float*)uni;                 // [22][512]
    __shared__ float sw2[NH][TI][24];
    __shared__ float wn[NH * TI][17];

    const int tid  = threadIdx.x;
    const int wave = tid >> 6;
    const int lane = tid & 63;
    const int l15  = lane & 15;
    const int quad = lane >> 4;
    const int i0   = blockIdx.x * TI;
    const int b    = blockIdx.y;

    // ---- P1: stage Q rows (8) and K band rows (22) as bf16 via glds ----
    for (int r = wave; r < TI; r += 4) {
        const bf16_t* g = qkb + (size_t)(b * SEQ + i0 + r) * 1024 + lane * 8;
        __builtin_amdgcn_global_load_lds((gbl_cvoid*)g, (lds_void*)(Qb + r * DIM), 16, 0, 0);
    }
    for (int r = wave; r < NROW; r += 4) {
        int jg = i0 - LR + r;
        jg = jg < 0 ? 0 : (jg > SEQ - 1 ? SEQ - 1 : jg);
        const bf16_t* g = qkb + (size_t)(b * SEQ + jg) * 1024 + DIM + lane * 8;
        __builtin_amdgcn_global_load_lds((gbl_cvoid*)g, (lds_void*)(Kb + r * DIM), 16, 0, 0);
    }
    __syncthreads();

    // ---- P2: MFMA scores.  wave handles heads 2w, 2w+1. ----
    #pragma unroll
    for (int hh = 0; hh < 2; ++hh) {
        const int h = wave * 2 + hh;
        f32x4 sacc[2] = {};
        #pragma unroll
        for (int s = 0; s < 2; ++s) {
            const bf16x8 aq = *(const bf16x8*)(Qb + l15 * DIM + h * DH + s * 32 + quad * 8);
            #pragma unroll
            for (int t = 0; t < 2; ++t) {
                const bf16x8 bk = *(const bf16x8*)(Kb + (t * 16 + l15) * DIM + h * DH + s * 32 + quad * 8);
                sacc[t] = __builtin_amdgcn_mfma_f32_16x16x32_bf16(aq, bk, sacc[t], 0, 0, 0);
            }
        }
        #pragma unroll
        for (int t = 0; t < 2; ++t) {
            const int jj = t * 16 + l15;
            if (jj < NROW) {
                #pragma unroll
                for (int r = 0; r < 4; ++r) {
                    const int ii = quad * 4 + r;
                    if (ii < TI) sw2[h][ii][jj] = sacc[t][r] * 0.125f;
                }
            }
        }
    }
    __syncthreads();

    // ---- P4: stage fp32 hs band via glds (over Qb/Kb region) ----
    for (int r = wave; r < NROW; r += 4) {
        int jg = i0 - LR + r;
        jg = jg < 0 ? 0 : (jg > SEQ - 1 ? SEQ - 1 : jg);
        const float* g0 = hs + ((size_t)b * SEQ + jg) * DIM + lane * 4;
        __builtin_amdgcn_global_load_lds((gbl_cvoid*)g0,         (lds_void*)(band + r * DIM),       16, 0, 0);
        __builtin_amdgcn_global_load_lds((gbl_cvoid*)(g0 + 256), (lds_void*)(band + r * DIM + 256), 16, 0, 0);
    }

    // ---- P3: softmax (tid<64), position-masked ----
    if (tid < NH * TI) {
        const int h  = tid >> 3;
        const int ii = tid & (TI - 1);
        const int i  = i0 + ii;
        float v[15], m = -1e30f;
        #pragma unroll
        for (int t = 0; t < 15; ++t) {
            const int jg = i - LR + t;
            v[t] = (jg >= 0 && jg < SEQ) ? sw2[h][ii][ii + t] : -1e30f;
            m = fmaxf(m, v[t]);
        }
        float sum = 0.f;
        #pragma unroll
        for (int t = 0; t < 15; ++t) { v[t] = __expf(v[t] - m); sum += v[t]; }
        const float inv = 1.f / sum;
        #pragma unroll
        for (int t = 0; t < 15; ++t) wn[tid][t] = v[t] * inv;
    }
    __syncthreads();

    // ---- P5: context ----
    {
        const int h  = tid >> 5;                // 0..7
        const int iq = (tid >> 4) & 1;          // 0..1
        const int dg = tid & 15;                // 0..15

        float wreg[4][15];
        #pragma unroll
        for (int t = 0; t < 4; ++t) {
            const int pair = h * TI + iq * 4 + t;
            #pragma unroll
            for (int j = 0; j < 15; ++j) wreg[t][j] = wn[pair][j];
        }

        const int r0 = iq * 4;
        float* op = out + ((size_t)(b * NH + h) * SEQ + i0 + iq * 4) * DIM;

        for (int c = 0; c < DIM / 64; ++c) {
            const int dbase = c * 64 + dg * 4;
            float4 a0 = {0,0,0,0}, a1 = {0,0,0,0}, a2 = {0,0,0,0}, a3 = {0,0,0,0};
            #pragma unroll
            for (int rr = 0; rr < 18; ++rr) {
                const float4 v = *(const float4*)&band[(r0 + rr) * DIM + dbase];
                if (rr <= 14) {
                    const float w = wreg[0][rr];
                    a0.x += w * v.x; a0.y += w * v.y; a0.z += w * v.z; a0.w += w * v.w;
                }
                if (rr >= 1 && rr <= 15) {
                    const float w = wreg[1][rr - 1];
                    a1.x += w * v.x; a1.y += w * v.y; a1.z += w * v.z; a1.w += w * v.w;
                }
                if (rr >= 2 && rr <= 16) {
                    const float w = wreg[2][rr - 2];
                    a2.x += w * v.x; a2.y += w * v.y; a2.z += w * v.z; a2.w += w * v.w;
                }
                if (rr >= 3) {
                    const float w = wreg[3][rr - 3];
                    a3.x += w * v.x; a3.y += w * v.y; a3.z += w * v.z; a3.w += w * v.w;
                }
            }
            *(float4*)(op + (size_t)0 * DIM + dbase) = a0;
            *(float4*)(op + (size_t)1 * DIM + dbase) = a1;
            *(float4*)(op + (size_t)2 * DIM + dbase) = a2;
            *(float4*)(op + (size_t)3 * DIM + dbase) = a3;
        }
    }
}

// ---------------------------------------------------------------------------
extern "C" void kernel_launch(void* const* d_in, const int* in_sizes, int n_in,
                              void* d_out, int out_size, void* d_ws, size_t ws_size,
                              hipStream_t stream)
{
    const float* hs = (const float*)d_in[0];
    const float* Wq = (const float*)d_in[1];
    const float* Wk = (const float*)d_in[2];
    float* out = (float*)d_out;

    bf16_t* hsb = (bf16_t*)d_ws;                          // 4 MB
    bf16_t* Wt  = (bf16_t*)((char*)d_ws + (4 << 20));     // 1 MB
    bf16_t* qkb = (bf16_t*)((char*)d_ws + (5 << 20));     // 8 MB

    prep<<<1024 + 128, 256, 0, stream>>>(hs, Wq, Wk, hsb, Wt);
    qk_gemm_mfma<<<dim3(4096 / 64, 1024 / 128), 256, 0, stream>>>(hsb, Wt, qkb);
    local_attn4<<<dim3(SEQ / TI, 2), 256, 0, stream>>>(hs, qkb, out);
}